// Round 9
// baseline (1003.549 us; speedup 1.0000x reference)
//
#include <hip/hip_runtime.h>
#include <hip/hip_bf16.h>

#define NN 20000
#define NE 100000
#define HID 256
#define HO 1024   // HEADS*OUT
#define HEADS 4
#define OUT 256

typedef __attribute__((ext_vector_type(8))) short bf16x8;
typedef __attribute__((ext_vector_type(4))) float f32x4;

__device__ inline ushort f2bf(float f) {
    union { float f; unsigned u; } v; v.f = f;
    unsigned r = v.u + 0x7FFFu + ((v.u >> 16) & 1u);  // RNE
    return (ushort)(r >> 16);
}
__device__ inline float bf2f(ushort b) {
    union { unsigned u; float f; } v; v.u = ((unsigned)b) << 16;
    return v.f;
}

// ---------------------------------------------------------------------------
// K1: h_bf = bf16(relu(x @ W_ne + b_ne))   x:[N,7] W:[7,256]
__global__ __launch_bounds__(256) void node_enc_kernel(
    const float* __restrict__ x, const float* __restrict__ W,
    const float* __restrict__ b, ushort* __restrict__ h)
{
    int n = blockIdx.x;
    int c = threadIdx.x;
    __shared__ float xs[8];
    if (threadIdx.x < 7) xs[threadIdx.x] = x[n * 7 + threadIdx.x];
    __syncthreads();
    float acc = b[c];
#pragma unroll
    for (int k = 0; k < 7; k++) acc += xs[k] * W[k * HID + c];
    h[(size_t)n * HID + c] = f2bf(fmaxf(acc, 0.f));
}

// ---------------------------------------------------------------------------
// WT[n][k] = bf16(W[k][n])   W:[K,N]  grid=dim3(K, N/256)
__global__ __launch_bounds__(256) void transpose_bf16_kernel(
    const float* __restrict__ W, ushort* __restrict__ WT, int K, int N)
{
    int k = blockIdx.x;
    int n = blockIdx.y * 256 + threadIdx.x;
    WT[(size_t)n * K + k] = f2bf(W[(size_t)k * N + n]);
}

// ---------------------------------------------------------------------------
// biasH[c] = b_d1[c] + sum_k conv_bias[k] * W_d1[k,c]
__global__ __launch_bounds__(256) void biasH_kernel(
    const float* __restrict__ conv_bias, const float* __restrict__ W_d1,
    const float* __restrict__ b_d1, float* __restrict__ biasH)
{
    int c = threadIdx.x;
    float acc = b_d1[c];
    for (int k = 0; k < HO; k++) acc += conv_bias[k] * W_d1[(size_t)k * HID + c];
    biasH[c] = acc;
}

// ---------------------------------------------------------------------------
// CSR build
__global__ __launch_bounds__(256) void hist_kernel(
    const int* __restrict__ ei, int* __restrict__ deg)
{
    int e = blockIdx.x * blockDim.x + threadIdx.x;
    if (e >= NE) return;
    atomicAdd(&deg[ei[NE + e]], 1);
}

// 1 block x 1024 threads: thread t owns 20 nodes in registers;
// wave shfl-scan + cross-wave LDS scan of 16 wave totals.
__global__ __launch_bounds__(1024) void scan_kernel(
    const int* __restrict__ deg, int* __restrict__ rowptr, int* __restrict__ cursor)
{
    const int CH = 20;   // 1024*20 = 20480 >= 20000
    int t = threadIdx.x;
    int start = t * CH;
    int d[CH];
    int local = 0;
#pragma unroll
    for (int i = 0; i < CH; i++) {
        int idx = start + i;
        d[i] = (idx < NN) ? deg[idx] : 0;
        local += d[i];
    }
    int incl = local;
#pragma unroll
    for (int off = 1; off < 64; off <<= 1) {
        int v = __shfl_up(incl, off);
        if ((t & 63) >= off) incl += v;
    }
    __shared__ int waveTot[16];
    int wv = t >> 6;
    if ((t & 63) == 63) waveTot[wv] = incl;
    __syncthreads();
    if (t < 16) {
        int v = waveTot[t];
        int s = v;
#pragma unroll
        for (int off = 1; off < 16; off <<= 1) {
            int u = __shfl_up(s, off);
            if (t >= off) s += u;
        }
        waveTot[t] = s - v;   // exclusive prefix of wave totals
    }
    __syncthreads();
    int run = (incl - local) + waveTot[wv];
#pragma unroll
    for (int i = 0; i < CH; i++) {
        int idx = start + i;
        if (idx < NN) { rowptr[idx] = run; cursor[idx] = run; }
        run += d[i];
    }
    if (t == 1023) rowptr[NN] = run;
}

__global__ __launch_bounds__(256) void scatter_kernel(
    const int* __restrict__ ei, int* __restrict__ cursor, int* __restrict__ eidx)
{
    int e = blockIdx.x * blockDim.x + threadIdx.x;
    if (e >= NE) return;
    int d = ei[NE + e];
    int pos = atomicAdd(&cursor[d], 1);
    eidx[pos] = e;
}

// ---------------------------------------------------------------------------
// MFMA GEMM: C[M,256] = A[M,256] @ BT^T. B-fragments preloaded to registers
// as one 32-load burst (latency hides under A staging + barrier).
// MODE 0: C bf16 = res + bias.  MODE 1: C f32 +=.
template <int MODE>
__global__ __launch_bounds__(256) void mfma_gemm_kernel(
    const ushort* __restrict__ A, const ushort* __restrict__ BT, int ldBT,
    const float* __restrict__ bias, void* __restrict__ Cv, int M)
{
    __shared__ __align__(16) ushort As[64][264];
    int t = threadIdx.x, w = t >> 6, lane = t & 63;
    int l15 = lane & 15, l4 = lane >> 4;
    int row0 = blockIdx.x * 64;

    // preload all B fragments for this wave's 64 cols (64 VGPR, 32-load burst)
    bf16x8 bf[8][4];
#pragma unroll
    for (int kk = 0; kk < 8; kk++)
#pragma unroll
        for (int ct = 0; ct < 4; ct++) {
            int n = w * 64 + ct * 16 + l15;
            bf[kk][ct] = *(const bf16x8*)&BT[(size_t)n * ldBT + kk * 32 + l4 * 8];
        }

    {   // stage A tile
        int r = t >> 2, c0 = (t & 3) * 64;
        int row = row0 + r;
        if (row < M) {
            const ushort* src = &A[(size_t)row * 256 + c0];
#pragma unroll
            for (int c = 0; c < 8; c++)
                *(bf16x8*)&As[r][c0 + c * 8] = *(const bf16x8*)&src[c * 8];
        } else {
            bf16x8 z = (bf16x8){0, 0, 0, 0, 0, 0, 0, 0};
#pragma unroll
            for (int c = 0; c < 8; c++) *(bf16x8*)&As[r][c0 + c * 8] = z;
        }
    }
    __syncthreads();
    f32x4 acc[4][4] = {};
#pragma unroll
    for (int kk = 0; kk < 8; kk++) {
        bf16x8 a[4];
#pragma unroll
        for (int rt = 0; rt < 4; rt++)
            a[rt] = *(const bf16x8*)&As[rt * 16 + l15][kk * 32 + l4 * 8];
#pragma unroll
        for (int rt = 0; rt < 4; rt++)
#pragma unroll
            for (int ct = 0; ct < 4; ct++)
                acc[rt][ct] = __builtin_amdgcn_mfma_f32_16x16x32_bf16(
                    a[rt], bf[kk][ct], acc[rt][ct], 0, 0, 0);
    }
    if constexpr (MODE == 0) {
        ushort* C = (ushort*)Cv;
        float bv[4];
#pragma unroll
        for (int ct = 0; ct < 4; ct++) bv[ct] = bias[w * 64 + ct * 16 + l15];
#pragma unroll
        for (int rt = 0; rt < 4; rt++)
#pragma unroll
            for (int ct = 0; ct < 4; ct++)
#pragma unroll
                for (int r = 0; r < 4; r++) {
                    int row = row0 + rt * 16 + l4 * 4 + r;
                    if (row < M)
                        C[(size_t)row * 256 + w * 64 + ct * 16 + l15] =
                            f2bf(acc[rt][ct][r] + bv[ct]);
                }
    } else {
        float* C = (float*)Cv;
#pragma unroll
        for (int rt = 0; rt < 4; rt++)
#pragma unroll
            for (int ct = 0; ct < 4; ct++)
#pragma unroll
                for (int r = 0; r < 4; r++) {
                    int row = row0 + rt * 16 + l4 * 4 + r;
                    if (row < M)
                        C[(size_t)row * 256 + w * 64 + ct * 16 + l15] += acc[rt][ct][r];
                }
    }
}

// ---------------------------------------------------------------------------
// Fused edge kernel (per head): 32 edges/group, grid-stride over groups.
// WeT fragments preloaded ONCE per block (64 VGPR, 32-load burst), reused
// across ~4 groups -> WeT L2 traffic cut 4x and out of the inner loop.
#define EPB 32
#define EDGE_GRID 768
__global__ __launch_bounds__(256) void edge_mfma_logits_kernel(
    const float* __restrict__ edge_attr, const float* __restrict__ W_ee,
    const float* __restrict__ b_ee, const ushort* __restrict__ WeTh,
    const float* __restrict__ b_e_h, const float* __restrict__ att_h,
    const ushort* __restrict__ xl, const ushort* __restrict__ xr,
    const int* __restrict__ ei, float* __restrict__ lbuf4, int h)
{
    __shared__ __align__(16) ushort As[EPB][264];   // 16.9 KB; reused as XL/XR
    __shared__ float ea[EPB * 7];
    __shared__ int sArr[EPB], dArr[EPB];
    __shared__ float red[4][EPB];
    ushort (*XL)[264] = As;        // rows 0..15
    ushort (*XR)[264] = As + 16;   // rows 16..31
    int t = threadIdx.x, w = t >> 6, lane = t & 63;
    int l15 = lane & 15, l4 = lane >> 4;

    // hoisted invariants
    bf16x8 bfr[8][4];
#pragma unroll
    for (int kk = 0; kk < 8; kk++)
#pragma unroll
        for (int ct = 0; ct < 4; ct++) {
            int n = w * 64 + ct * 16 + l15;
            bfr[kk][ct] = *(const bf16x8*)&WeTh[(size_t)n * 256 + kk * 32 + l4 * 8];
        }
    float w7[7];
#pragma unroll
    for (int k = 0; k < 7; k++) w7[k] = W_ee[k * HID + t];
    float bee = b_ee[t];
    float bev[4], atv[4];
#pragma unroll
    for (int ct = 0; ct < 4; ct++) {
        int col = w * 64 + ct * 16 + l15;
        bev[ct] = b_e_h[col];
        atv[ct] = att_h[col];
    }
    int sli = t >> 4;           // staging row 0..15
    int sch = (t & 15) * 16;    // staging col chunk (32B)

    for (int g = blockIdx.x; g < NE / EPB; g += EDGE_GRID) {
        int e0 = g * EPB;
        if (t < EPB * 7) ea[t] = edge_attr[(size_t)e0 * 7 + t];
        if (t < EPB) {
            sArr[t] = ei[e0 + t];
            dArr[t] = ei[NE + e0 + t];
        }
        __syncthreads();

        // ---- phase A: e_enc ----
#pragma unroll 4
        for (int r = 0; r < EPB; r++) {
            float acc = bee;
#pragma unroll
            for (int k = 0; k < 7; k++) acc += w7[k] * ea[r * 7 + k];
            As[r][t] = f2bf(fmaxf(acc, 0.f));
        }
        __syncthreads();

        // ---- phase B: MFMA (pure LDS + registers) ----
        f32x4 acc[2][4] = {};
#pragma unroll
        for (int kk = 0; kk < 8; kk++) {
            bf16x8 a[2];
#pragma unroll
            for (int rt = 0; rt < 2; rt++)
                a[rt] = *(const bf16x8*)&As[rt * 16 + l15][kk * 32 + l4 * 8];
#pragma unroll
            for (int rt = 0; rt < 2; rt++)
#pragma unroll
                for (int ct = 0; ct < 4; ct++)
                    acc[rt][ct] = __builtin_amdgcn_mfma_f32_16x16x32_bf16(
                        a[rt], bfr[kk][ct], acc[rt][ct], 0, 0, 0);
        }
        __syncthreads();   // e_enc consumed; reuse As as XL/XR

        // ---- phase C: stage gathers per 16-edge group, compute logits ----
        float lp[2][4];
#pragma unroll
        for (int rt = 0; rt < 2; rt++) {
            {
                int sRow = sArr[rt * 16 + sli], dRow = dArr[rt * 16 + sli];
                const ushort* ps = &xl[(size_t)sRow * 256 + sch];
                const ushort* pd = &xr[(size_t)dRow * 256 + sch];
                bf16x8 v0 = *(const bf16x8*)ps;
                bf16x8 v1 = *(const bf16x8*)(ps + 8);
                bf16x8 v2 = *(const bf16x8*)pd;
                bf16x8 v3 = *(const bf16x8*)(pd + 8);
                *(bf16x8*)&XL[sli][sch]     = v0;
                *(bf16x8*)&XL[sli][sch + 8] = v1;
                *(bf16x8*)&XR[sli][sch]     = v2;
                *(bf16x8*)&XR[sli][sch + 8] = v3;
            }
            __syncthreads();
#pragma unroll
            for (int r = 0; r < 4; r++) {
                int li = l4 * 4 + r;
                float p = 0.f;
#pragma unroll
                for (int ct = 0; ct < 4; ct++) {
                    int col = w * 64 + ct * 16 + l15;
                    float z = acc[rt][ct][r] + bev[ct] +
                              bf2f(XL[li][col]) + bf2f(XR[li][col]);
                    z = (z > 0.f) ? z : 0.2f * z;
                    p += z * atv[ct];
                }
                lp[rt][r] = p;
            }
            __syncthreads();
        }

#pragma unroll
        for (int off = 1; off < 16; off <<= 1)
#pragma unroll
            for (int rt = 0; rt < 2; rt++)
#pragma unroll
                for (int r = 0; r < 4; r++)
                    lp[rt][r] += __shfl_xor(lp[rt][r], off);
        if (l15 == 0)
#pragma unroll
            for (int rt = 0; rt < 2; rt++)
#pragma unroll
                for (int r = 0; r < 4; r++)
                    red[w][rt * 16 + l4 * 4 + r] = lp[rt][r];
        __syncthreads();
        if (t < EPB) {
            float v = red[0][t] + red[1][t] + red[2][t] + red[3][t];
            lbuf4[(size_t)(e0 + t) * 4 + h] = v;
        }
        __syncthreads();   // red/As safe for next group
    }
}

// ---------------------------------------------------------------------------
// Fused segment softmax + aggregation (per head). One wave per dst node.
__global__ __launch_bounds__(256) void softmax_agg_kernel(
    const float* __restrict__ lbuf4, const int* __restrict__ rowptr,
    const int* __restrict__ eidx, const int* __restrict__ ei,
    const ushort* __restrict__ xl, ushort* __restrict__ agg, int h)
{
    int wv = threadIdx.x >> 6, lane = threadIdx.x & 63;
    int n = blockIdx.x * 4 + wv;
    if (n >= NN) return;
    int r0 = rowptr[n], r1 = rowptr[n + 1];
    float m = -3.4e38f;
    for (int j = r0; j < r1; j++)
        m = fmaxf(m, lbuf4[(size_t)eidx[j] * 4 + h]);
    float denom = 0.f;
    for (int j = r0; j < r1; j++)
        denom += __expf(lbuf4[(size_t)eidx[j] * 4 + h] - m);
    float rd = (denom > 0.f) ? 1.f / denom : 0.f;
    float a0 = 0.f, a1 = 0.f, a2 = 0.f, a3 = 0.f;
    for (int j = r0; j < r1; j++) {
        int e = eidx[j];
        int s = ei[e];
        float alpha = __expf(lbuf4[(size_t)e * 4 + h] - m) * rd;
        ushort4 xv = *(const ushort4*)&xl[(size_t)s * 256 + lane * 4];
        a0 += alpha * bf2f(xv.x); a1 += alpha * bf2f(xv.y);
        a2 += alpha * bf2f(xv.z); a3 += alpha * bf2f(xv.w);
    }
    ushort4 o;
    o.x = f2bf(a0); o.y = f2bf(a1); o.z = f2bf(a2); o.w = f2bf(a3);
    *(ushort4*)&agg[(size_t)n * 256 + lane * 4] = o;
}

// ---------------------------------------------------------------------------
// hid = relu(hid + biasH)
__global__ __launch_bounds__(256) void hid_relu_kernel(
    float* __restrict__ hid, const float* __restrict__ biasH)
{
    int g = blockIdx.x * blockDim.x + threadIdx.x;
    if (g >= NN * HID) return;
    hid[g] = fmaxf(hid[g] + biasH[g & (HID - 1)], 0.f);
}

// ---------------------------------------------------------------------------
// out = sigmoid(hid @ W_d2 + b_d2)
__global__ __launch_bounds__(256) void final_kernel(
    const float* __restrict__ hid, const float* __restrict__ W_d2,
    const float* __restrict__ b_d2, float* __restrict__ out)
{
    int g = blockIdx.x * blockDim.x + threadIdx.x;
    if (g >= NN * 6) return;
    int n = g / 6, j = g % 6;
    float acc = b_d2[j];
    const float4* hp = reinterpret_cast<const float4*>(&hid[(size_t)n * HID]);
#pragma unroll 4
    for (int k4 = 0; k4 < HID / 4; k4++) {
        float4 hv = hp[k4];
        int k = k4 * 4;
        acc += hv.x * W_d2[(k + 0) * 6 + j] + hv.y * W_d2[(k + 1) * 6 + j] +
               hv.z * W_d2[(k + 2) * 6 + j] + hv.w * W_d2[(k + 3) * 6 + j];
    }
    out[g] = 1.f / (1.f + __expf(-acc));
}

// ---------------------------------------------------------------------------
extern "C" void kernel_launch(void* const* d_in, const int* in_sizes, int n_in,
                              void* d_out, int out_size, void* d_ws, size_t ws_size,
                              hipStream_t stream)
{
    const float* x         = (const float*)d_in[0];
    const float* edge_attr = (const float*)d_in[1];
    const float* W_ne = (const float*)d_in[2];  const float* b_ne = (const float*)d_in[3];
    const float* W_ee = (const float*)d_in[4];  const float* b_ee = (const float*)d_in[5];
    const float* W_l  = (const float*)d_in[6];  const float* b_l  = (const float*)d_in[7];
    const float* W_r  = (const float*)d_in[8];  const float* b_r  = (const float*)d_in[9];
    const float* W_e  = (const float*)d_in[10]; const float* b_e  = (const float*)d_in[11];
    const float* att  = (const float*)d_in[12];
    const float* conv_bias = (const float*)d_in[13];
    const float* W_d1 = (const float*)d_in[14]; const float* b_d1 = (const float*)d_in[15];
    const float* W_d2 = (const float*)d_in[16]; const float* b_d2 = (const float*)d_in[17];
    const int*   ei   = (const int*)d_in[18];
    float* out = (float*)d_out;

    const size_t NODEH = (size_t)NN * HID;   // 5.12M
    char* p = (char*)d_ws;
    ushort* h_bf   = (ushort*)p;  p += NODEH * 2;
    ushort* xl_bf  = (ushort*)p;  p += NODEH * 2;
    ushort* xr_bf  = (ushort*)p;  p += NODEH * 2;
    ushort* agg_bf = (ushort*)p;  p += NODEH * 2;
    float*  hid    = (float*)p;   p += NODEH * 4;
    float*  lbuf4  = (float*)p;   p += (size_t)NE * HEADS * 4;
    int*    deg    = (int*)p;     p += (size_t)NN * 4;
    int*    rowptr = (int*)p;     p += (size_t)(NN + 1) * 4;
    int*    cursor = (int*)p;     p += (size_t)NN * 4;
    int*    eidx   = (int*)p;     p += (size_t)NE * 4;
    float*  biasH  = (float*)p;   p += HID * 4;
    ushort* WlT    = (ushort*)p;  p += (size_t)HO * HID * 2;   // [1024][256]
    ushort* WrT    = (ushort*)p;  p += (size_t)HO * HID * 2;
    ushort* WeT    = (ushort*)p;  p += (size_t)HO * HID * 2;
    ushort* Wd1T   = (ushort*)p;  p += (size_t)HID * HO * 2;   // [256][1024]
    if ((size_t)(p - (char*)d_ws) > ws_size) return;  // clean fail, no OOB

    hipMemsetAsync(deg, 0, (size_t)NN * 4, stream);
    hipMemsetAsync(hid, 0, NODEH * 4, stream);

    node_enc_kernel<<<NN, 256, 0, stream>>>(x, W_ne, b_ne, h_bf);
    biasH_kernel<<<1, 256, 0, stream>>>(conv_bias, W_d1, b_d1, biasH);

    transpose_bf16_kernel<<<dim3(HID, HO / 256), 256, 0, stream>>>(W_l,  WlT,  HID, HO);
    transpose_bf16_kernel<<<dim3(HID, HO / 256), 256, 0, stream>>>(W_r,  WrT,  HID, HO);
    transpose_bf16_kernel<<<dim3(HID, HO / 256), 256, 0, stream>>>(W_e,  WeT,  HID, HO);
    transpose_bf16_kernel<<<dim3(HO, HID / 256), 256, 0, stream>>>(W_d1, Wd1T, HO,  HID);

    hist_kernel<<<(NE + 255) / 256, 256, 0, stream>>>(ei, deg);
    scan_kernel<<<1, 1024, 0, stream>>>(deg, rowptr, cursor);
    scatter_kernel<<<(NE + 255) / 256, 256, 0, stream>>>(ei, cursor, eidx);

    const int gemmGrid = (NN + 63) / 64;     // 313

    for (int hh = 0; hh < HEADS; hh++) {
        mfma_gemm_kernel<0><<<gemmGrid, 256, 0, stream>>>(
            h_bf, WlT + (size_t)hh * OUT * HID, HID, b_l + hh * OUT, xl_bf, NN);
        mfma_gemm_kernel<0><<<gemmGrid, 256, 0, stream>>>(
            h_bf, WrT + (size_t)hh * OUT * HID, HID, b_r + hh * OUT, xr_bf, NN);

        edge_mfma_logits_kernel<<<EDGE_GRID, 256, 0, stream>>>(
            edge_attr, W_ee, b_ee, WeT + (size_t)hh * OUT * HID,
            b_e + hh * OUT, att + hh * OUT, xl_bf, xr_bf, ei, lbuf4, hh);

        softmax_agg_kernel<<<(NN + 3) / 4, 256, 0, stream>>>(
            lbuf4, rowptr, eidx, ei, xl_bf, agg_bf, hh);

        mfma_gemm_kernel<1><<<gemmGrid, 256, 0, stream>>>(
            agg_bf, Wd1T + hh * OUT, HO, nullptr, hid, NN);
    }

    hid_relu_kernel<<<(NN * HID + 255) / 256, 256, 0, stream>>>(hid, biasH);
    final_kernel<<<(NN * 6 + 255) / 256, 256, 0, stream>>>(hid, W_d2, b_d2, out);
}

// Round 10
// 766.622 us; speedup vs baseline: 1.3091x; 1.3091x over previous
//
#include <hip/hip_runtime.h>
#include <hip/hip_bf16.h>

#define NN 20000
#define NE 100000
#define HID 256
#define HO 1024   // HEADS*OUT
#define HEADS 4
#define OUT 256

typedef __attribute__((ext_vector_type(8))) short bf16x8;
typedef __attribute__((ext_vector_type(4))) float f32x4;

__device__ inline ushort f2bf(float f) {
    union { float f; unsigned u; } v; v.f = f;
    unsigned r = v.u + 0x7FFFu + ((v.u >> 16) & 1u);  // RNE
    return (ushort)(r >> 16);
}
__device__ inline float bf2f(ushort b) {
    union { unsigned u; float f; } v; v.u = ((unsigned)b) << 16;
    return v.f;
}

// ---------------------------------------------------------------------------
// K1: h_bf = bf16(relu(x @ W_ne + b_ne))   x:[N,7] W:[7,256]
__global__ __launch_bounds__(256) void node_enc_kernel(
    const float* __restrict__ x, const float* __restrict__ W,
    const float* __restrict__ b, ushort* __restrict__ h)
{
    int n = blockIdx.x;
    int c = threadIdx.x;
    __shared__ float xs[8];
    if (threadIdx.x < 7) xs[threadIdx.x] = x[n * 7 + threadIdx.x];
    __syncthreads();
    float acc = b[c];
#pragma unroll
    for (int k = 0; k < 7; k++) acc += xs[k] * W[k * HID + c];
    h[(size_t)n * HID + c] = f2bf(fmaxf(acc, 0.f));
}

// ---------------------------------------------------------------------------
// WT[n][k] = bf16(W[k][n])   W:[K,N]  grid=dim3(K, N/256)
__global__ __launch_bounds__(256) void transpose_bf16_kernel(
    const float* __restrict__ W, ushort* __restrict__ WT, int K, int N)
{
    int k = blockIdx.x;
    int n = blockIdx.y * 256 + threadIdx.x;
    WT[(size_t)n * K + k] = f2bf(W[(size_t)k * N + n]);
}

// ---------------------------------------------------------------------------
// biasH[c] = b_d1[c] + sum_k conv_bias[k] * W_d1[k,c]
__global__ __launch_bounds__(256) void biasH_kernel(
    const float* __restrict__ conv_bias, const float* __restrict__ W_d1,
    const float* __restrict__ b_d1, float* __restrict__ biasH)
{
    int c = threadIdx.x;
    float acc = b_d1[c];
    for (int k = 0; k < HO; k++) acc += conv_bias[k] * W_d1[(size_t)k * HID + c];
    biasH[c] = acc;
}

// ---------------------------------------------------------------------------
// CSR build
__global__ __launch_bounds__(256) void hist_kernel(
    const int* __restrict__ ei, int* __restrict__ deg)
{
    int e = blockIdx.x * blockDim.x + threadIdx.x;
    if (e >= NE) return;
    atomicAdd(&deg[ei[NE + e]], 1);
}

// 1 block x 1024 threads: thread t owns 20 nodes in registers;
// wave shfl-scan + cross-wave LDS scan of 16 wave totals.
__global__ __launch_bounds__(1024) void scan_kernel(
    const int* __restrict__ deg, int* __restrict__ rowptr, int* __restrict__ cursor)
{
    const int CH = 20;   // 1024*20 = 20480 >= 20000
    int t = threadIdx.x;
    int start = t * CH;
    int d[CH];
    int local = 0;
#pragma unroll
    for (int i = 0; i < CH; i++) {
        int idx = start + i;
        d[i] = (idx < NN) ? deg[idx] : 0;
        local += d[i];
    }
    int incl = local;
#pragma unroll
    for (int off = 1; off < 64; off <<= 1) {
        int v = __shfl_up(incl, off);
        if ((t & 63) >= off) incl += v;
    }
    __shared__ int waveTot[16];
    int wv = t >> 6;
    if ((t & 63) == 63) waveTot[wv] = incl;
    __syncthreads();
    if (t < 16) {
        int v = waveTot[t];
        int s = v;
#pragma unroll
        for (int off = 1; off < 16; off <<= 1) {
            int u = __shfl_up(s, off);
            if (t >= off) s += u;
        }
        waveTot[t] = s - v;   // exclusive prefix of wave totals
    }
    __syncthreads();
    int run = (incl - local) + waveTot[wv];
#pragma unroll
    for (int i = 0; i < CH; i++) {
        int idx = start + i;
        if (idx < NN) { rowptr[idx] = run; cursor[idx] = run; }
        run += d[i];
    }
    if (t == 1023) rowptr[NN] = run;
}

// scatter: also materialize srcs/dsts in dst-sorted order (contiguous reads
// downstream; removes double-indirection ei[eidx[j]]).
__global__ __launch_bounds__(256) void scatter_kernel(
    const int* __restrict__ ei, int* __restrict__ cursor, int* __restrict__ eidx,
    int* __restrict__ srcs, int* __restrict__ dsts)
{
    int e = blockIdx.x * blockDim.x + threadIdx.x;
    if (e >= NE) return;
    int d = ei[NE + e];
    int pos = atomicAdd(&cursor[d], 1);
    eidx[pos] = e;
    srcs[pos] = ei[e];
    dsts[pos] = d;
}

// ---------------------------------------------------------------------------
// MFMA GEMM (R7-proven): C[M,256] = A[M,256] @ BT^T, A staged in LDS.
// MODE 0: C bf16 = res + bias.  MODE 1: C f32 +=.
template <int MODE>
__global__ __launch_bounds__(256) void mfma_gemm_kernel(
    const ushort* __restrict__ A, const ushort* __restrict__ BT, int ldBT,
    const float* __restrict__ bias, void* __restrict__ Cv, int M)
{
    __shared__ __align__(16) ushort As[64][264];
    int t = threadIdx.x, w = t >> 6, lane = t & 63;
    int l15 = lane & 15, l4 = lane >> 4;
    int row0 = blockIdx.x * 64;
    {   // stage A tile: thread t -> row t>>2, 128B chunk (t&3)
        int r = t >> 2, c0 = (t & 3) * 64;
        int row = row0 + r;
        if (row < M) {
            const ushort* src = &A[(size_t)row * 256 + c0];
#pragma unroll
            for (int c = 0; c < 8; c++)
                *(bf16x8*)&As[r][c0 + c * 8] = *(const bf16x8*)&src[c * 8];
        } else {
            bf16x8 z = (bf16x8){0, 0, 0, 0, 0, 0, 0, 0};
#pragma unroll
            for (int c = 0; c < 8; c++) *(bf16x8*)&As[r][c0 + c * 8] = z;
        }
    }
    __syncthreads();
    f32x4 acc[4][4] = {};
    for (int k0 = 0; k0 < 256; k0 += 32) {
        bf16x8 a[4], b[4];
#pragma unroll
        for (int rt = 0; rt < 4; rt++)
            a[rt] = *(const bf16x8*)&As[rt * 16 + l15][k0 + l4 * 8];
#pragma unroll
        for (int ct = 0; ct < 4; ct++) {
            int n = w * 64 + ct * 16 + l15;
            b[ct] = *(const bf16x8*)&BT[(size_t)n * ldBT + k0 + l4 * 8];
        }
#pragma unroll
        for (int rt = 0; rt < 4; rt++)
#pragma unroll
            for (int ct = 0; ct < 4; ct++)
                acc[rt][ct] = __builtin_amdgcn_mfma_f32_16x16x32_bf16(
                    a[rt], b[ct], acc[rt][ct], 0, 0, 0);
    }
    if constexpr (MODE == 0) {
        ushort* C = (ushort*)Cv;
        float bv[4];
#pragma unroll
        for (int ct = 0; ct < 4; ct++) bv[ct] = bias[w * 64 + ct * 16 + l15];
#pragma unroll
        for (int rt = 0; rt < 4; rt++)
#pragma unroll
            for (int ct = 0; ct < 4; ct++)
#pragma unroll
                for (int r = 0; r < 4; r++) {
                    int row = row0 + rt * 16 + l4 * 4 + r;
                    if (row < M)
                        C[(size_t)row * 256 + w * 64 + ct * 16 + l15] =
                            f2bf(acc[rt][ct][r] + bv[ct]);
                }
    } else {
        float* C = (float*)Cv;
#pragma unroll
        for (int rt = 0; rt < 4; rt++)
#pragma unroll
            for (int ct = 0; ct < 4; ct++)
#pragma unroll
                for (int r = 0; r < 4; r++) {
                    int row = row0 + rt * 16 + l4 * 4 + r;
                    if (row < M)
                        C[(size_t)row * 256 + w * 64 + ct * 16 + l15] += acc[rt][ct][r];
                }
    }
}

// ---------------------------------------------------------------------------
// Fused edge kernel (per head): 32 DST-SORTED edges/block, 4 waves.
// Sorted order => consecutive edges share dst (mean degree 5) so xr-row
// staging hits L1/L2 instead of L3; logits land contiguously at position j.
#define EPB 32
__global__ __launch_bounds__(256) void edge_mfma_logits_kernel(
    const float* __restrict__ edge_attr, const float* __restrict__ W_ee,
    const float* __restrict__ b_ee, const ushort* __restrict__ WeTh,
    const float* __restrict__ b_e_h, const float* __restrict__ att_h,
    const ushort* __restrict__ xl, const ushort* __restrict__ xr,
    const int* __restrict__ eidx, const int* __restrict__ srcs,
    const int* __restrict__ dsts, float* __restrict__ lbuf4, int h)
{
    __shared__ __align__(16) ushort As[EPB][264];   // 16.9 KB; reused as XL/XR
    __shared__ float ea[EPB * 7];
    __shared__ int sArr[EPB], dArr[EPB];
    __shared__ float red[4][EPB];
    ushort (*XL)[264] = As;        // rows 0..15
    ushort (*XR)[264] = As + 16;   // rows 16..31
    int j0 = blockIdx.x * EPB;     // sorted-position base; NE % EPB == 0
    int t = threadIdx.x, w = t >> 6, lane = t & 63;
    int l15 = lane & 15, l4 = lane >> 4;

    if (t < EPB * 7) {
        int e = eidx[j0 + t / 7];                 // original edge id (gather)
        ea[t] = edge_attr[(size_t)e * 7 + t % 7];
    }
    if (t < EPB) {
        sArr[t] = srcs[j0 + t];                   // contiguous
        dArr[t] = dsts[j0 + t];                   // contiguous
    }
    float w7[7];
#pragma unroll
    for (int k = 0; k < 7; k++) w7[k] = W_ee[k * HID + t];
    float bee = b_ee[t];
    __syncthreads();

    // ---- phase A: e_enc ----
#pragma unroll 4
    for (int r = 0; r < EPB; r++) {
        float acc = bee;
#pragma unroll
        for (int k = 0; k < 7; k++) acc += w7[k] * ea[r * 7 + k];
        As[r][t] = f2bf(fmaxf(acc, 0.f));
    }
    __syncthreads();

    // ---- phase B: MFMA ----
    f32x4 acc[2][4] = {};
    for (int k0 = 0; k0 < 256; k0 += 32) {
        bf16x8 a[2], b[4];
#pragma unroll
        for (int rt = 0; rt < 2; rt++)
            a[rt] = *(const bf16x8*)&As[rt * 16 + l15][k0 + l4 * 8];
#pragma unroll
        for (int ct = 0; ct < 4; ct++) {
            int n = w * 64 + ct * 16 + l15;
            b[ct] = *(const bf16x8*)&WeTh[(size_t)n * 256 + k0 + l4 * 8];
        }
#pragma unroll
        for (int rt = 0; rt < 2; rt++)
#pragma unroll
            for (int ct = 0; ct < 4; ct++)
                acc[rt][ct] = __builtin_amdgcn_mfma_f32_16x16x32_bf16(
                    a[rt], b[ct], acc[rt][ct], 0, 0, 0);
    }

    float bev[4], atv[4];
#pragma unroll
    for (int ct = 0; ct < 4; ct++) {
        int col = w * 64 + ct * 16 + l15;
        bev[ct] = b_e_h[col];
        atv[ct] = att_h[col];
    }
    __syncthreads();   // e_enc consumed; reuse As as XL/XR

    // ---- phase C: stage gathers per 16-edge group, compute logits ----
    int sli = t >> 4;           // staging row 0..15
    int sch = (t & 15) * 16;    // staging col chunk (32B)
    float lp[2][4];
#pragma unroll
    for (int rt = 0; rt < 2; rt++) {
        {
            int sRow = sArr[rt * 16 + sli], dRow = dArr[rt * 16 + sli];
            const ushort* ps = &xl[(size_t)sRow * 256 + sch];
            const ushort* pd = &xr[(size_t)dRow * 256 + sch];
            bf16x8 v0 = *(const bf16x8*)ps;
            bf16x8 v1 = *(const bf16x8*)(ps + 8);
            bf16x8 v2 = *(const bf16x8*)pd;
            bf16x8 v3 = *(const bf16x8*)(pd + 8);
            *(bf16x8*)&XL[sli][sch]     = v0;
            *(bf16x8*)&XL[sli][sch + 8] = v1;
            *(bf16x8*)&XR[sli][sch]     = v2;
            *(bf16x8*)&XR[sli][sch + 8] = v3;
        }
        __syncthreads();
#pragma unroll
        for (int r = 0; r < 4; r++) {
            int li = l4 * 4 + r;
            float p = 0.f;
#pragma unroll
            for (int ct = 0; ct < 4; ct++) {
                int col = w * 64 + ct * 16 + l15;
                float z = acc[rt][ct][r] + bev[ct] +
                          bf2f(XL[li][col]) + bf2f(XR[li][col]);
                z = (z > 0.f) ? z : 0.2f * z;
                p += z * atv[ct];
            }
            lp[rt][r] = p;
        }
        __syncthreads();
    }

#pragma unroll
    for (int off = 1; off < 16; off <<= 1)
#pragma unroll
        for (int rt = 0; rt < 2; rt++)
#pragma unroll
            for (int r = 0; r < 4; r++)
                lp[rt][r] += __shfl_xor(lp[rt][r], off);
    if (l15 == 0)
#pragma unroll
        for (int rt = 0; rt < 2; rt++)
#pragma unroll
            for (int r = 0; r < 4; r++)
                red[w][rt * 16 + l4 * 4 + r] = lp[rt][r];
    __syncthreads();
    if (t < EPB) {
        float v = red[0][t] + red[1][t] + red[2][t] + red[3][t];
        lbuf4[(size_t)(j0 + t) * 4 + h] = v;   // sorted position
    }
}

// ---------------------------------------------------------------------------
// Fused segment softmax + aggregation (per head). One wave per dst node.
// lbuf4 + srcs are dst-sorted => all per-edge scalar reads are contiguous.
__global__ __launch_bounds__(256) void softmax_agg_kernel(
    const float* __restrict__ lbuf4, const int* __restrict__ rowptr,
    const int* __restrict__ srcs, const ushort* __restrict__ xl,
    ushort* __restrict__ agg, int h)
{
    int wv = threadIdx.x >> 6, lane = threadIdx.x & 63;
    int n = blockIdx.x * 4 + wv;
    if (n >= NN) return;
    int r0 = rowptr[n], r1 = rowptr[n + 1];
    float m = -3.4e38f;
    for (int j = r0; j < r1; j++)
        m = fmaxf(m, lbuf4[(size_t)j * 4 + h]);
    float denom = 0.f;
    for (int j = r0; j < r1; j++)
        denom += __expf(lbuf4[(size_t)j * 4 + h] - m);
    float rd = (denom > 0.f) ? 1.f / denom : 0.f;
    float a0 = 0.f, a1 = 0.f, a2 = 0.f, a3 = 0.f;
    for (int j = r0; j < r1; j++) {
        int s = srcs[j];
        float alpha = __expf(lbuf4[(size_t)j * 4 + h] - m) * rd;
        ushort4 xv = *(const ushort4*)&xl[(size_t)s * 256 + lane * 4];
        a0 += alpha * bf2f(xv.x); a1 += alpha * bf2f(xv.y);
        a2 += alpha * bf2f(xv.z); a3 += alpha * bf2f(xv.w);
    }
    ushort4 o;
    o.x = f2bf(a0); o.y = f2bf(a1); o.z = f2bf(a2); o.w = f2bf(a3);
    *(ushort4*)&agg[(size_t)n * 256 + lane * 4] = o;
}

// ---------------------------------------------------------------------------
// hid = relu(hid + biasH)
__global__ __launch_bounds__(256) void hid_relu_kernel(
    float* __restrict__ hid, const float* __restrict__ biasH)
{
    int g = blockIdx.x * blockDim.x + threadIdx.x;
    if (g >= NN * HID) return;
    hid[g] = fmaxf(hid[g] + biasH[g & (HID - 1)], 0.f);
}

// ---------------------------------------------------------------------------
// out = sigmoid(hid @ W_d2 + b_d2)
__global__ __launch_bounds__(256) void final_kernel(
    const float* __restrict__ hid, const float* __restrict__ W_d2,
    const float* __restrict__ b_d2, float* __restrict__ out)
{
    int g = blockIdx.x * blockDim.x + threadIdx.x;
    if (g >= NN * 6) return;
    int n = g / 6, j = g % 6;
    float acc = b_d2[j];
    const float4* hp = reinterpret_cast<const float4*>(&hid[(size_t)n * HID]);
#pragma unroll 4
    for (int k4 = 0; k4 < HID / 4; k4++) {
        float4 hv = hp[k4];
        int k = k4 * 4;
        acc += hv.x * W_d2[(k + 0) * 6 + j] + hv.y * W_d2[(k + 1) * 6 + j] +
               hv.z * W_d2[(k + 2) * 6 + j] + hv.w * W_d2[(k + 3) * 6 + j];
    }
    out[g] = 1.f / (1.f + __expf(-acc));
}

// ---------------------------------------------------------------------------
extern "C" void kernel_launch(void* const* d_in, const int* in_sizes, int n_in,
                              void* d_out, int out_size, void* d_ws, size_t ws_size,
                              hipStream_t stream)
{
    const float* x         = (const float*)d_in[0];
    const float* edge_attr = (const float*)d_in[1];
    const float* W_ne = (const float*)d_in[2];  const float* b_ne = (const float*)d_in[3];
    const float* W_ee = (const float*)d_in[4];  const float* b_ee = (const float*)d_in[5];
    const float* W_l  = (const float*)d_in[6];  const float* b_l  = (const float*)d_in[7];
    const float* W_r  = (const float*)d_in[8];  const float* b_r  = (const float*)d_in[9];
    const float* W_e  = (const float*)d_in[10]; const float* b_e  = (const float*)d_in[11];
    const float* att  = (const float*)d_in[12];
    const float* conv_bias = (const float*)d_in[13];
    const float* W_d1 = (const float*)d_in[14]; const float* b_d1 = (const float*)d_in[15];
    const float* W_d2 = (const float*)d_in[16]; const float* b_d2 = (const float*)d_in[17];
    const int*   ei   = (const int*)d_in[18];
    float* out = (float*)d_out;

    const size_t NODEH = (size_t)NN * HID;   // 5.12M
    char* p = (char*)d_ws;
    ushort* h_bf   = (ushort*)p;  p += NODEH * 2;
    ushort* xl_bf  = (ushort*)p;  p += NODEH * 2;
    ushort* xr_bf  = (ushort*)p;  p += NODEH * 2;
    ushort* agg_bf = (ushort*)p;  p += NODEH * 2;
    float*  hid    = (float*)p;   p += NODEH * 4;
    float*  lbuf4  = (float*)p;   p += (size_t)NE * HEADS * 4;
    int*    deg    = (int*)p;     p += (size_t)NN * 4;
    int*    rowptr = (int*)p;     p += (size_t)(NN + 1) * 4;
    int*    cursor = (int*)p;     p += (size_t)NN * 4;
    int*    eidx   = (int*)p;     p += (size_t)NE * 4;
    int*    srcs   = (int*)p;     p += (size_t)NE * 4;
    int*    dsts   = (int*)p;     p += (size_t)NE * 4;
    float*  biasH  = (float*)p;   p += HID * 4;
    ushort* WlT    = (ushort*)p;  p += (size_t)HO * HID * 2;   // [1024][256]
    ushort* WrT    = (ushort*)p;  p += (size_t)HO * HID * 2;
    ushort* WeT    = (ushort*)p;  p += (size_t)HO * HID * 2;
    ushort* Wd1T   = (ushort*)p;  p += (size_t)HID * HO * 2;   // [256][1024]
    if ((size_t)(p - (char*)d_ws) > ws_size) return;  // clean fail, no OOB

    hipMemsetAsync(deg, 0, (size_t)NN * 4, stream);
    hipMemsetAsync(hid, 0, NODEH * 4, stream);

    node_enc_kernel<<<NN, 256, 0, stream>>>(x, W_ne, b_ne, h_bf);
    biasH_kernel<<<1, 256, 0, stream>>>(conv_bias, W_d1, b_d1, biasH);

    transpose_bf16_kernel<<<dim3(HID, HO / 256), 256, 0, stream>>>(W_l,  WlT,  HID, HO);
    transpose_bf16_kernel<<<dim3(HID, HO / 256), 256, 0, stream>>>(W_r,  WrT,  HID, HO);
    transpose_bf16_kernel<<<dim3(HID, HO / 256), 256, 0, stream>>>(W_e,  WeT,  HID, HO);
    transpose_bf16_kernel<<<dim3(HO, HID / 256), 256, 0, stream>>>(W_d1, Wd1T, HO,  HID);

    hist_kernel<<<(NE + 255) / 256, 256, 0, stream>>>(ei, deg);
    scan_kernel<<<1, 1024, 0, stream>>>(deg, rowptr, cursor);
    scatter_kernel<<<(NE + 255) / 256, 256, 0, stream>>>(ei, cursor, eidx, srcs, dsts);

    const int gemmGrid = (NN + 63) / 64;     // 313
    const int edgeGrid = NE / EPB;           // 3125

    for (int hh = 0; hh < HEADS; hh++) {
        mfma_gemm_kernel<0><<<gemmGrid, 256, 0, stream>>>(
            h_bf, WlT + (size_t)hh * OUT * HID, HID, b_l + hh * OUT, xl_bf, NN);
        mfma_gemm_kernel<0><<<gemmGrid, 256, 0, stream>>>(
            h_bf, WrT + (size_t)hh * OUT * HID, HID, b_r + hh * OUT, xr_bf, NN);

        edge_mfma_logits_kernel<<<edgeGrid, 256, 0, stream>>>(
            edge_attr, W_ee, b_ee, WeT + (size_t)hh * OUT * HID,
            b_e + hh * OUT, att + hh * OUT, xl_bf, xr_bf,
            eidx, srcs, dsts, lbuf4, hh);

        softmax_agg_kernel<<<(NN + 3) / 4, 256, 0, stream>>>(
            lbuf4, rowptr, srcs, xl_bf, agg_bf, hh);

        mfma_gemm_kernel<1><<<gemmGrid, 256, 0, stream>>>(
            agg_bf, Wd1T + hh * OUT, HO, nullptr, hid, NN);
    }

    hid_relu_kernel<<<(NN * HID + 255) / 256, 256, 0, stream>>>(hid, biasH);
    final_kernel<<<(NN * 6 + 255) / 256, 256, 0, stream>>>(hid, W_d2, b_d2, out);
}

// Round 11
// 755.130 us; speedup vs baseline: 1.3290x; 1.0152x over previous
//
#include <hip/hip_runtime.h>
#include <hip/hip_bf16.h>

#define NN 20000
#define NE 100000
#define HID 256
#define HO 1024   // HEADS*OUT
#define HEADS 4
#define OUT 256

typedef __attribute__((ext_vector_type(8))) short bf16x8;
typedef __attribute__((ext_vector_type(4))) float f32x4;

__device__ inline ushort f2bf(float f) {
    union { float f; unsigned u; } v; v.f = f;
    unsigned r = v.u + 0x7FFFu + ((v.u >> 16) & 1u);  // RNE
    return (ushort)(r >> 16);
}
__device__ inline float bf2f(ushort b) {
    union { unsigned u; float f; } v; v.u = ((unsigned)b) << 16;
    return v.f;
}

// ---------------------------------------------------------------------------
// K1: h_bf = bf16(relu(x @ W_ne + b_ne))   x:[N,7] W:[7,256]
__global__ __launch_bounds__(256) void node_enc_kernel(
    const float* __restrict__ x, const float* __restrict__ W,
    const float* __restrict__ b, ushort* __restrict__ h)
{
    int n = blockIdx.x;
    int c = threadIdx.x;
    __shared__ float xs[8];
    if (threadIdx.x < 7) xs[threadIdx.x] = x[n * 7 + threadIdx.x];
    __syncthreads();
    float acc = b[c];
#pragma unroll
    for (int k = 0; k < 7; k++) acc += xs[k] * W[k * HID + c];
    h[(size_t)n * HID + c] = f2bf(fmaxf(acc, 0.f));
}

// ---------------------------------------------------------------------------
// WT[n][k] = bf16(W[k][n])   W:[K,N]  grid=dim3(K, N/256)
__global__ __launch_bounds__(256) void transpose_bf16_kernel(
    const float* __restrict__ W, ushort* __restrict__ WT, int K, int N)
{
    int k = blockIdx.x;
    int n = blockIdx.y * 256 + threadIdx.x;
    WT[(size_t)n * K + k] = f2bf(W[(size_t)k * N + n]);
}

// ---------------------------------------------------------------------------
// biasH[c] = b_d1[c] + sum_k conv_bias[k] * W_d1[k,c]
__global__ __launch_bounds__(256) void biasH_kernel(
    const float* __restrict__ conv_bias, const float* __restrict__ W_d1,
    const float* __restrict__ b_d1, float* __restrict__ biasH)
{
    int c = threadIdx.x;
    float acc = b_d1[c];
    for (int k = 0; k < HO; k++) acc += conv_bias[k] * W_d1[(size_t)k * HID + c];
    biasH[c] = acc;
}

// ---------------------------------------------------------------------------
// CSR build
__global__ __launch_bounds__(256) void hist_kernel(
    const int* __restrict__ ei, int* __restrict__ deg)
{
    int e = blockIdx.x * blockDim.x + threadIdx.x;
    if (e >= NE) return;
    atomicAdd(&deg[ei[NE + e]], 1);
}

// 1 block x 1024 threads: thread t owns 20 nodes in registers;
// wave shfl-scan + cross-wave LDS scan of 16 wave totals.
__global__ __launch_bounds__(1024) void scan_kernel(
    const int* __restrict__ deg, int* __restrict__ rowptr, int* __restrict__ cursor)
{
    const int CH = 20;   // 1024*20 = 20480 >= 20000
    int t = threadIdx.x;
    int start = t * CH;
    int d[CH];
    int local = 0;
#pragma unroll
    for (int i = 0; i < CH; i++) {
        int idx = start + i;
        d[i] = (idx < NN) ? deg[idx] : 0;
        local += d[i];
    }
    int incl = local;
#pragma unroll
    for (int off = 1; off < 64; off <<= 1) {
        int v = __shfl_up(incl, off);
        if ((t & 63) >= off) incl += v;
    }
    __shared__ int waveTot[16];
    int wv = t >> 6;
    if ((t & 63) == 63) waveTot[wv] = incl;
    __syncthreads();
    if (t < 16) {
        int v = waveTot[t];
        int s = v;
#pragma unroll
        for (int off = 1; off < 16; off <<= 1) {
            int u = __shfl_up(s, off);
            if (t >= off) s += u;
        }
        waveTot[t] = s - v;   // exclusive prefix of wave totals
    }
    __syncthreads();
    int run = (incl - local) + waveTot[wv];
#pragma unroll
    for (int i = 0; i < CH; i++) {
        int idx = start + i;
        if (idx < NN) { rowptr[idx] = run; cursor[idx] = run; }
        run += d[i];
    }
    if (t == 1023) rowptr[NN] = run;
}

// scatter: also materialize srcs/dsts in dst-sorted order.
__global__ __launch_bounds__(256) void scatter_kernel(
    const int* __restrict__ ei, int* __restrict__ cursor, int* __restrict__ eidx,
    int* __restrict__ srcs, int* __restrict__ dsts)
{
    int e = blockIdx.x * blockDim.x + threadIdx.x;
    if (e >= NE) return;
    int d = ei[NE + e];
    int pos = atomicAdd(&cursor[d], 1);
    eidx[pos] = e;
    srcs[pos] = ei[e];
    dsts[pos] = d;
}

// ---------------------------------------------------------------------------
// MFMA GEMM (proven): C[M,256] = A[M,256] @ BT^T, A staged in LDS.
// MODE 0: C bf16 = res + bias.  MODE 1: C f32 +=.
template <int MODE>
__global__ __launch_bounds__(256) void mfma_gemm_kernel(
    const ushort* __restrict__ A, const ushort* __restrict__ BT, int ldBT,
    const float* __restrict__ bias, void* __restrict__ Cv, int M)
{
    __shared__ __align__(16) ushort As[64][264];
    int t = threadIdx.x, w = t >> 6, lane = t & 63;
    int l15 = lane & 15, l4 = lane >> 4;
    int row0 = blockIdx.x * 64;
    {   // stage A tile: thread t -> row t>>2, 128B chunk (t&3)
        int r = t >> 2, c0 = (t & 3) * 64;
        int row = row0 + r;
        if (row < M) {
            const ushort* src = &A[(size_t)row * 256 + c0];
#pragma unroll
            for (int c = 0; c < 8; c++)
                *(bf16x8*)&As[r][c0 + c * 8] = *(const bf16x8*)&src[c * 8];
        } else {
            bf16x8 z = (bf16x8){0, 0, 0, 0, 0, 0, 0, 0};
#pragma unroll
            for (int c = 0; c < 8; c++) *(bf16x8*)&As[r][c0 + c * 8] = z;
        }
    }
    __syncthreads();
    f32x4 acc[4][4] = {};
    for (int k0 = 0; k0 < 256; k0 += 32) {
        bf16x8 a[4], b[4];
#pragma unroll
        for (int rt = 0; rt < 4; rt++)
            a[rt] = *(const bf16x8*)&As[rt * 16 + l15][k0 + l4 * 8];
#pragma unroll
        for (int ct = 0; ct < 4; ct++) {
            int n = w * 64 + ct * 16 + l15;
            b[ct] = *(const bf16x8*)&BT[(size_t)n * ldBT + k0 + l4 * 8];
        }
#pragma unroll
        for (int rt = 0; rt < 4; rt++)
#pragma unroll
            for (int ct = 0; ct < 4; ct++)
                acc[rt][ct] = __builtin_amdgcn_mfma_f32_16x16x32_bf16(
                    a[rt], b[ct], acc[rt][ct], 0, 0, 0);
    }
    if constexpr (MODE == 0) {
        ushort* C = (ushort*)Cv;
        float bv[4];
#pragma unroll
        for (int ct = 0; ct < 4; ct++) bv[ct] = bias[w * 64 + ct * 16 + l15];
#pragma unroll
        for (int rt = 0; rt < 4; rt++)
#pragma unroll
            for (int ct = 0; ct < 4; ct++)
#pragma unroll
                for (int r = 0; r < 4; r++) {
                    int row = row0 + rt * 16 + l4 * 4 + r;
                    if (row < M)
                        C[(size_t)row * 256 + w * 64 + ct * 16 + l15] =
                            f2bf(acc[rt][ct][r] + bv[ct]);
                }
    } else {
        float* C = (float*)Cv;
#pragma unroll
        for (int rt = 0; rt < 4; rt++)
#pragma unroll
            for (int ct = 0; ct < 4; ct++)
#pragma unroll
                for (int r = 0; r < 4; r++) {
                    int row = row0 + rt * 16 + l4 * 4 + r;
                    if (row < M)
                        C[(size_t)row * 256 + w * 64 + ct * 16 + l15] += acc[rt][ct][r];
                }
    }
}

// ---------------------------------------------------------------------------
// Fused edge kernel (per head): 32 DST-SORTED edges/block, 4 waves.
// Register-dieted + __launch_bounds__(256,8): target VGPR <= 64 so LDS
// (18.9KB -> 8 blocks/CU) becomes the binding limit => ~32 waves/CU ceiling.
#define EPB 32
__global__ __launch_bounds__(256, 8) void edge_mfma_logits_kernel(
    const float* __restrict__ edge_attr, const float* __restrict__ W_ee,
    const float* __restrict__ b_ee, const ushort* __restrict__ WeTh,
    const float* __restrict__ b_e_h, const float* __restrict__ att_h,
    const ushort* __restrict__ xl, const ushort* __restrict__ xr,
    const int* __restrict__ eidx, const int* __restrict__ srcs,
    const int* __restrict__ dsts, float* __restrict__ lbuf4, int h)
{
    __shared__ __align__(16) ushort As[EPB][264];   // 16.9 KB; reused as XL/XR
    __shared__ float ea[EPB * 7];
    __shared__ int sArr[EPB], dArr[EPB];
    __shared__ float red[4][EPB];
    ushort (*XL)[264] = As;        // rows 0..15
    ushort (*XR)[264] = As + 16;   // rows 16..31
    int j0 = blockIdx.x * EPB;     // sorted-position base; NE % EPB == 0
    int t = threadIdx.x, w = t >> 6, lane = t & 63;
    int l15 = lane & 15, l4 = lane >> 4;

    if (t < EPB * 7) {
        int e = eidx[j0 + t / 7];                 // original edge id (gather)
        ea[t] = edge_attr[(size_t)e * 7 + t % 7];
    }
    if (t < EPB) {
        sArr[t] = srcs[j0 + t];                   // contiguous
        dArr[t] = dsts[j0 + t];                   // contiguous
    }
    __syncthreads();

    // ---- phase A: e_enc (w7/bee scoped here; dead after) ----
    {
        float w7[7];
#pragma unroll
        for (int k = 0; k < 7; k++) w7[k] = W_ee[k * HID + t];
        float bee = b_ee[t];
#pragma unroll 4
        for (int r = 0; r < EPB; r++) {
            float acc = bee;
#pragma unroll
            for (int k = 0; k < 7; k++) acc += w7[k] * ea[r * 7 + k];
            As[r][t] = f2bf(fmaxf(acc, 0.f));
        }
    }
    __syncthreads();

    // ---- phase B: MFMA ----
    f32x4 acc[2][4] = {};
    for (int k0 = 0; k0 < 256; k0 += 32) {
        bf16x8 a[2], b[4];
#pragma unroll
        for (int rt = 0; rt < 2; rt++)
            a[rt] = *(const bf16x8*)&As[rt * 16 + l15][k0 + l4 * 8];
#pragma unroll
        for (int ct = 0; ct < 4; ct++) {
            int n = w * 64 + ct * 16 + l15;
            b[ct] = *(const bf16x8*)&WeTh[(size_t)n * 256 + k0 + l4 * 8];
        }
#pragma unroll
        for (int rt = 0; rt < 2; rt++)
#pragma unroll
            for (int ct = 0; ct < 4; ct++)
                acc[rt][ct] = __builtin_amdgcn_mfma_f32_16x16x32_bf16(
                    a[rt], b[ct], acc[rt][ct], 0, 0, 0);
    }
    __syncthreads();   // e_enc consumed; reuse As as XL/XR

    // ---- phase C: stage gathers per 16-edge group, logits + immediate reduce ----
    {
        float bev[4], atv[4];
#pragma unroll
        for (int ct = 0; ct < 4; ct++) {
            int col = w * 64 + ct * 16 + l15;
            bev[ct] = b_e_h[col];
            atv[ct] = att_h[col];
        }
        int sli = t >> 4;           // staging row 0..15
        int sch = (t & 15) * 16;    // staging col chunk (32B)
#pragma unroll
        for (int rt = 0; rt < 2; rt++) {
            {
                int sRow = sArr[rt * 16 + sli], dRow = dArr[rt * 16 + sli];
                const ushort* ps = &xl[(size_t)sRow * 256 + sch];
                const ushort* pd = &xr[(size_t)dRow * 256 + sch];
                bf16x8 v0 = *(const bf16x8*)ps;
                bf16x8 v1 = *(const bf16x8*)(ps + 8);
                bf16x8 v2 = *(const bf16x8*)pd;
                bf16x8 v3 = *(const bf16x8*)(pd + 8);
                *(bf16x8*)&XL[sli][sch]     = v0;
                *(bf16x8*)&XL[sli][sch + 8] = v1;
                *(bf16x8*)&XR[sli][sch]     = v2;
                *(bf16x8*)&XR[sli][sch + 8] = v3;
            }
            __syncthreads();
            float lp[4];
#pragma unroll
            for (int r = 0; r < 4; r++) {
                int li = l4 * 4 + r;
                float p = 0.f;
#pragma unroll
                for (int ct = 0; ct < 4; ct++) {
                    int col = w * 64 + ct * 16 + l15;
                    float z = acc[rt][ct][r] + bev[ct] +
                              bf2f(XL[li][col]) + bf2f(XR[li][col]);
                    z = (z > 0.f) ? z : 0.2f * z;
                    p += z * atv[ct];
                }
                lp[r] = p;
            }
#pragma unroll
            for (int off = 1; off < 16; off <<= 1)
#pragma unroll
                for (int r = 0; r < 4; r++)
                    lp[r] += __shfl_xor(lp[r], off);
            if (l15 == 0)
#pragma unroll
                for (int r = 0; r < 4; r++)
                    red[w][rt * 16 + l4 * 4 + r] = lp[r];
            __syncthreads();
        }
    }

    if (t < EPB) {
        float v = red[0][t] + red[1][t] + red[2][t] + red[3][t];
        lbuf4[(size_t)(j0 + t) * 4 + h] = v;   // sorted position
    }
}

// ---------------------------------------------------------------------------
// Fused segment softmax + aggregation (per head). One wave per dst node.
// lbuf4 + srcs are dst-sorted => all per-edge scalar reads are contiguous.
__global__ __launch_bounds__(256) void softmax_agg_kernel(
    const float* __restrict__ lbuf4, const int* __restrict__ rowptr,
    const int* __restrict__ srcs, const ushort* __restrict__ xl,
    ushort* __restrict__ agg, int h)
{
    int wv = threadIdx.x >> 6, lane = threadIdx.x & 63;
    int n = blockIdx.x * 4 + wv;
    if (n >= NN) return;
    int r0 = rowptr[n], r1 = rowptr[n + 1];
    float m = -3.4e38f;
    for (int j = r0; j < r1; j++)
        m = fmaxf(m, lbuf4[(size_t)j * 4 + h]);
    float denom = 0.f;
    for (int j = r0; j < r1; j++)
        denom += __expf(lbuf4[(size_t)j * 4 + h] - m);
    float rd = (denom > 0.f) ? 1.f / denom : 0.f;
    float a0 = 0.f, a1 = 0.f, a2 = 0.f, a3 = 0.f;
    for (int j = r0; j < r1; j++) {
        int s = srcs[j];
        float alpha = __expf(lbuf4[(size_t)j * 4 + h] - m) * rd;
        ushort4 xv = *(const ushort4*)&xl[(size_t)s * 256 + lane * 4];
        a0 += alpha * bf2f(xv.x); a1 += alpha * bf2f(xv.y);
        a2 += alpha * bf2f(xv.z); a3 += alpha * bf2f(xv.w);
    }
    ushort4 o;
    o.x = f2bf(a0); o.y = f2bf(a1); o.z = f2bf(a2); o.w = f2bf(a3);
    *(ushort4*)&agg[(size_t)n * 256 + lane * 4] = o;
}

// ---------------------------------------------------------------------------
// hid = relu(hid + biasH)
__global__ __launch_bounds__(256) void hid_relu_kernel(
    float* __restrict__ hid, const float* __restrict__ biasH)
{
    int g = blockIdx.x * blockDim.x + threadIdx.x;
    if (g >= NN * HID) return;
    hid[g] = fmaxf(hid[g] + biasH[g & (HID - 1)], 0.f);
}

// ---------------------------------------------------------------------------
// out = sigmoid(hid @ W_d2 + b_d2)
__global__ __launch_bounds__(256) void final_kernel(
    const float* __restrict__ hid, const float* __restrict__ W_d2,
    const float* __restrict__ b_d2, float* __restrict__ out)
{
    int g = blockIdx.x * blockDim.x + threadIdx.x;
    if (g >= NN * 6) return;
    int n = g / 6, j = g % 6;
    float acc = b_d2[j];
    const float4* hp = reinterpret_cast<const float4*>(&hid[(size_t)n * HID]);
#pragma unroll 4
    for (int k4 = 0; k4 < HID / 4; k4++) {
        float4 hv = hp[k4];
        int k = k4 * 4;
        acc += hv.x * W_d2[(k + 0) * 6 + j] + hv.y * W_d2[(k + 1) * 6 + j] +
               hv.z * W_d2[(k + 2) * 6 + j] + hv.w * W_d2[(k + 3) * 6 + j];
    }
    out[g] = 1.f / (1.f + __expf(-acc));
}

// ---------------------------------------------------------------------------
extern "C" void kernel_launch(void* const* d_in, const int* in_sizes, int n_in,
                              void* d_out, int out_size, void* d_ws, size_t ws_size,
                              hipStream_t stream)
{
    const float* x         = (const float*)d_in[0];
    const float* edge_attr = (const float*)d_in[1];
    const float* W_ne = (const float*)d_in[2];  const float* b_ne = (const float*)d_in[3];
    const float* W_ee = (const float*)d_in[4];  const float* b_ee = (const float*)d_in[5];
    const float* W_l  = (const float*)d_in[6];  const float* b_l  = (const float*)d_in[7];
    const float* W_r  = (const float*)d_in[8];  const float* b_r  = (const float*)d_in[9];
    const float* W_e  = (const float*)d_in[10]; const float* b_e  = (const float*)d_in[11];
    const float* att  = (const float*)d_in[12];
    const float* conv_bias = (const float*)d_in[13];
    const float* W_d1 = (const float*)d_in[14]; const float* b_d1 = (const float*)d_in[15];
    const float* W_d2 = (const float*)d_in[16]; const float* b_d2 = (const float*)d_in[17];
    const int*   ei   = (const int*)d_in[18];
    float* out = (float*)d_out;

    const size_t NODEH = (size_t)NN * HID;   // 5.12M
    char* p = (char*)d_ws;
    ushort* h_bf   = (ushort*)p;  p += NODEH * 2;
    ushort* xl_bf  = (ushort*)p;  p += NODEH * 2;
    ushort* xr_bf  = (ushort*)p;  p += NODEH * 2;
    ushort* agg_bf = (ushort*)p;  p += NODEH * 2;
    float*  hid    = (float*)p;   p += NODEH * 4;
    float*  lbuf4  = (float*)p;   p += (size_t)NE * HEADS * 4;
    int*    deg    = (int*)p;     p += (size_t)NN * 4;
    int*    rowptr = (int*)p;     p += (size_t)(NN + 1) * 4;
    int*    cursor = (int*)p;     p += (size_t)NN * 4;
    int*    eidx   = (int*)p;     p += (size_t)NE * 4;
    int*    srcs   = (int*)p;     p += (size_t)NE * 4;
    int*    dsts   = (int*)p;     p += (size_t)NE * 4;
    float*  biasH  = (float*)p;   p += HID * 4;
    ushort* WlT    = (ushort*)p;  p += (size_t)HO * HID * 2;   // [1024][256]
    ushort* WrT    = (ushort*)p;  p += (size_t)HO * HID * 2;
    ushort* WeT    = (ushort*)p;  p += (size_t)HO * HID * 2;
    ushort* Wd1T   = (ushort*)p;  p += (size_t)HID * HO * 2;   // [256][1024]
    if ((size_t)(p - (char*)d_ws) > ws_size) return;  // clean fail, no OOB

    hipMemsetAsync(deg, 0, (size_t)NN * 4, stream);
    hipMemsetAsync(hid, 0, NODEH * 4, stream);

    node_enc_kernel<<<NN, 256, 0, stream>>>(x, W_ne, b_ne, h_bf);
    biasH_kernel<<<1, 256, 0, stream>>>(conv_bias, W_d1, b_d1, biasH);

    transpose_bf16_kernel<<<dim3(HID, HO / 256), 256, 0, stream>>>(W_l,  WlT,  HID, HO);
    transpose_bf16_kernel<<<dim3(HID, HO / 256), 256, 0, stream>>>(W_r,  WrT,  HID, HO);
    transpose_bf16_kernel<<<dim3(HID, HO / 256), 256, 0, stream>>>(W_e,  WeT,  HID, HO);
    transpose_bf16_kernel<<<dim3(HO, HID / 256), 256, 0, stream>>>(W_d1, Wd1T, HO,  HID);

    hist_kernel<<<(NE + 255) / 256, 256, 0, stream>>>(ei, deg);
    scan_kernel<<<1, 1024, 0, stream>>>(deg, rowptr, cursor);
    scatter_kernel<<<(NE + 255) / 256, 256, 0, stream>>>(ei, cursor, eidx, srcs, dsts);

    const int gemmGrid = (NN + 63) / 64;     // 313
    const int edgeGrid = NE / EPB;           // 3125

    for (int hh = 0; hh < HEADS; hh++) {
        mfma_gemm_kernel<0><<<gemmGrid, 256, 0, stream>>>(
            h_bf, WlT + (size_t)hh * OUT * HID, HID, b_l + hh * OUT, xl_bf, NN);
        mfma_gemm_kernel<0><<<gemmGrid, 256, 0, stream>>>(
            h_bf, WrT + (size_t)hh * OUT * HID, HID, b_r + hh * OUT, xr_bf, NN);

        edge_mfma_logits_kernel<<<edgeGrid, 256, 0, stream>>>(
            edge_attr, W_ee, b_ee, WeT + (size_t)hh * OUT * HID,
            b_e + hh * OUT, att + hh * OUT, xl_bf, xr_bf,
            eidx, srcs, dsts, lbuf4, hh);

        softmax_agg_kernel<<<(NN + 3) / 4, 256, 0, stream>>>(
            lbuf4, rowptr, srcs, xl_bf, agg_bf, hh);

        mfma_gemm_kernel<1><<<gemmGrid, 256, 0, stream>>>(
            agg_bf, Wd1T + hh * OUT, HO, nullptr, hid, NN);
    }

    hid_relu_kernel<<<(NN * HID + 255) / 256, 256, 0, stream>>>(hid, biasH);
    final_kernel<<<(NN * 6 + 255) / 256, 256, 0, stream>>>(hid, W_d2, b_d2, out);
}

// Round 12
// 568.272 us; speedup vs baseline: 1.7660x; 1.3288x over previous
//
#include <hip/hip_runtime.h>
#include <hip/hip_bf16.h>

#define NN 20000
#define NE 100000
#define HID 256
#define HO 1024   // HEADS*OUT
#define HEADS 4
#define OUT 256

typedef __attribute__((ext_vector_type(8))) short bf16x8;
typedef __attribute__((ext_vector_type(4))) float f32x4;

__device__ inline ushort f2bf(float f) {
    union { float f; unsigned u; } v; v.f = f;
    unsigned r = v.u + 0x7FFFu + ((v.u >> 16) & 1u);  // RNE
    return (ushort)(r >> 16);
}
__device__ inline float bf2f(ushort b) {
    union { unsigned u; float f; } v; v.u = ((unsigned)b) << 16;
    return v.f;
}

// ---------------------------------------------------------------------------
// K1: h_bf = bf16(relu(x @ W_ne + b_ne))   x:[N,7] W:[7,256]
__global__ __launch_bounds__(256) void node_enc_kernel(
    const float* __restrict__ x, const float* __restrict__ W,
    const float* __restrict__ b, ushort* __restrict__ h)
{
    int n = blockIdx.x;
    int c = threadIdx.x;
    __shared__ float xs[8];
    if (threadIdx.x < 7) xs[threadIdx.x] = x[n * 7 + threadIdx.x];
    __syncthreads();
    float acc = b[c];
#pragma unroll
    for (int k = 0; k < 7; k++) acc += xs[k] * W[k * HID + c];
    h[(size_t)n * HID + c] = f2bf(fmaxf(acc, 0.f));
}

// ---------------------------------------------------------------------------
// WT[n][k] = bf16(W[k][n])   W:[K,N]  grid=dim3(K, N/256)
__global__ __launch_bounds__(256) void transpose_bf16_kernel(
    const float* __restrict__ W, ushort* __restrict__ WT, int K, int N)
{
    int k = blockIdx.x;
    int n = blockIdx.y * 256 + threadIdx.x;
    WT[(size_t)n * K + k] = f2bf(W[(size_t)k * N + n]);
}

// ---------------------------------------------------------------------------
// biasH[c] = b_d1[c] + sum_k conv_bias[k] * W_d1[k,c]
__global__ __launch_bounds__(256) void biasH_kernel(
    const float* __restrict__ conv_bias, const float* __restrict__ W_d1,
    const float* __restrict__ b_d1, float* __restrict__ biasH)
{
    int c = threadIdx.x;
    float acc = b_d1[c];
    for (int k = 0; k < HO; k++) acc += conv_bias[k] * W_d1[(size_t)k * HID + c];
    biasH[c] = acc;
}

// ---------------------------------------------------------------------------
// CSR build
__global__ __launch_bounds__(256) void hist_kernel(
    const int* __restrict__ ei, int* __restrict__ deg)
{
    int e = blockIdx.x * blockDim.x + threadIdx.x;
    if (e >= NE) return;
    atomicAdd(&deg[ei[NE + e]], 1);
}

__global__ __launch_bounds__(1024) void scan_kernel(
    const int* __restrict__ deg, int* __restrict__ rowptr, int* __restrict__ cursor)
{
    const int CH = 20;   // 1024*20 = 20480 >= 20000
    int t = threadIdx.x;
    int start = t * CH;
    int d[CH];
    int local = 0;
#pragma unroll
    for (int i = 0; i < CH; i++) {
        int idx = start + i;
        d[i] = (idx < NN) ? deg[idx] : 0;
        local += d[i];
    }
    int incl = local;
#pragma unroll
    for (int off = 1; off < 64; off <<= 1) {
        int v = __shfl_up(incl, off);
        if ((t & 63) >= off) incl += v;
    }
    __shared__ int waveTot[16];
    int wv = t >> 6;
    if ((t & 63) == 63) waveTot[wv] = incl;
    __syncthreads();
    if (t < 16) {
        int v = waveTot[t];
        int s = v;
#pragma unroll
        for (int off = 1; off < 16; off <<= 1) {
            int u = __shfl_up(s, off);
            if (t >= off) s += u;
        }
        waveTot[t] = s - v;
    }
    __syncthreads();
    int run = (incl - local) + waveTot[wv];
#pragma unroll
    for (int i = 0; i < CH; i++) {
        int idx = start + i;
        if (idx < NN) { rowptr[idx] = run; cursor[idx] = run; }
        run += d[i];
    }
    if (t == 1023) rowptr[NN] = run;
}

__global__ __launch_bounds__(256) void scatter_kernel(
    const int* __restrict__ ei, int* __restrict__ cursor, int* __restrict__ eidx,
    int* __restrict__ srcs, int* __restrict__ dsts)
{
    int e = blockIdx.x * blockDim.x + threadIdx.x;
    if (e >= NE) return;
    int d = ei[NE + e];
    int pos = atomicAdd(&cursor[d], 1);
    eidx[pos] = e;
    srcs[pos] = ei[e];
    dsts[pos] = d;
}

// ---------------------------------------------------------------------------
// xl/xr GEMM: C[M,1024] col-tile 256 per blockIdx.y.
// A[M,256] staged in LDS; BT rows = output cols, 256 k each.
__global__ __launch_bounds__(256) void qkv_gemm_kernel(
    const ushort* __restrict__ A, const ushort* __restrict__ BT,
    const float* __restrict__ bias, ushort* __restrict__ C, int M)
{
    __shared__ __align__(16) ushort As[64][264];
    int t = threadIdx.x, w = t >> 6, lane = t & 63;
    int l15 = lane & 15, l4 = lane >> 4;
    int row0 = blockIdx.x * 64;
    int colOff = blockIdx.y * 256;
    {
        int r = t >> 2, c0 = (t & 3) * 64;
        int row = row0 + r;
        if (row < M) {
            const ushort* src = &A[(size_t)row * 256 + c0];
#pragma unroll
            for (int c = 0; c < 8; c++)
                *(bf16x8*)&As[r][c0 + c * 8] = *(const bf16x8*)&src[c * 8];
        } else {
            bf16x8 z = (bf16x8){0, 0, 0, 0, 0, 0, 0, 0};
#pragma unroll
            for (int c = 0; c < 8; c++) *(bf16x8*)&As[r][c0 + c * 8] = z;
        }
    }
    __syncthreads();
    f32x4 acc[4][4] = {};
    for (int k0 = 0; k0 < 256; k0 += 32) {
        bf16x8 a[4], b[4];
#pragma unroll
        for (int rt = 0; rt < 4; rt++)
            a[rt] = *(const bf16x8*)&As[rt * 16 + l15][k0 + l4 * 8];
#pragma unroll
        for (int ct = 0; ct < 4; ct++) {
            int n = colOff + w * 64 + ct * 16 + l15;
            b[ct] = *(const bf16x8*)&BT[(size_t)n * 256 + k0 + l4 * 8];
        }
#pragma unroll
        for (int rt = 0; rt < 4; rt++)
#pragma unroll
            for (int ct = 0; ct < 4; ct++)
                acc[rt][ct] = __builtin_amdgcn_mfma_f32_16x16x32_bf16(
                    a[rt], b[ct], acc[rt][ct], 0, 0, 0);
    }
    float bv[4];
#pragma unroll
    for (int ct = 0; ct < 4; ct++) bv[ct] = bias[colOff + w * 64 + ct * 16 + l15];
#pragma unroll
    for (int rt = 0; rt < 4; rt++)
#pragma unroll
        for (int ct = 0; ct < 4; ct++)
#pragma unroll
            for (int r = 0; r < 4; r++) {
                int row = row0 + rt * 16 + l4 * 4 + r;
                if (row < M)
                    C[(size_t)row * 1024 + colOff + w * 64 + ct * 16 + l15] =
                        f2bf(acc[rt][ct][r] + bv[ct]);
            }
}

// ---------------------------------------------------------------------------
// Decoder GEMM: C[M,256] = relu(A[M,1024] @ BT[256,1024]^T + biasH), bf16 out.
__global__ __launch_bounds__(256) void dec_gemm_kernel(
    const ushort* __restrict__ A, const ushort* __restrict__ BT,
    const float* __restrict__ biasH, ushort* __restrict__ C, int M)
{
    __shared__ __align__(16) ushort As[64][264];
    int t = threadIdx.x, w = t >> 6, lane = t & 63;
    int l15 = lane & 15, l4 = lane >> 4;
    int row0 = blockIdx.x * 64;
    f32x4 acc[4][4] = {};
    for (int kc = 0; kc < 4; kc++) {
        if (kc) __syncthreads();
        {
            int r = t >> 2, c0 = (t & 3) * 64;
            int row = row0 + r;
            if (row < M) {
                const ushort* src = &A[(size_t)row * 1024 + kc * 256 + c0];
#pragma unroll
                for (int c = 0; c < 8; c++)
                    *(bf16x8*)&As[r][c0 + c * 8] = *(const bf16x8*)&src[c * 8];
            } else {
                bf16x8 z = (bf16x8){0, 0, 0, 0, 0, 0, 0, 0};
#pragma unroll
                for (int c = 0; c < 8; c++) *(bf16x8*)&As[r][c0 + c * 8] = z;
            }
        }
        __syncthreads();
        for (int k0 = 0; k0 < 256; k0 += 32) {
            bf16x8 a[4], b[4];
#pragma unroll
            for (int rt = 0; rt < 4; rt++)
                a[rt] = *(const bf16x8*)&As[rt * 16 + l15][k0 + l4 * 8];
#pragma unroll
            for (int ct = 0; ct < 4; ct++) {
                int n = w * 64 + ct * 16 + l15;
                b[ct] = *(const bf16x8*)&BT[(size_t)n * 1024 + kc * 256 + k0 + l4 * 8];
            }
#pragma unroll
            for (int rt = 0; rt < 4; rt++)
#pragma unroll
                for (int ct = 0; ct < 4; ct++)
                    acc[rt][ct] = __builtin_amdgcn_mfma_f32_16x16x32_bf16(
                        a[rt], b[ct], acc[rt][ct], 0, 0, 0);
        }
    }
    float bv[4];
#pragma unroll
    for (int ct = 0; ct < 4; ct++) bv[ct] = biasH[w * 64 + ct * 16 + l15];
#pragma unroll
    for (int rt = 0; rt < 4; rt++)
#pragma unroll
        for (int ct = 0; ct < 4; ct++)
#pragma unroll
            for (int r = 0; r < 4; r++) {
                int row = row0 + rt * 16 + l4 * 4 + r;
                if (row < M)
                    C[(size_t)row * 256 + w * 64 + ct * 16 + l15] =
                        f2bf(fmaxf(acc[rt][ct][r] + bv[ct], 0.f));
            }
}

// ---------------------------------------------------------------------------
// Fused edge kernel, ALL HEADS in one dispatch: 32 dst-sorted edges/block.
// Phase A once; per head: MFMA (b-loads + gather staging overlap) ->
// one barrier -> logits for both 16-edge groups -> one barrier.
#define EPB 32
__global__ __launch_bounds__(256, 4) void edge_mfma_logits_kernel(
    const float* __restrict__ edge_attr, const float* __restrict__ W_ee,
    const float* __restrict__ b_ee, const ushort* __restrict__ WeT,
    const float* __restrict__ b_e, const float* __restrict__ att,
    const ushort* __restrict__ xl, const ushort* __restrict__ xr,
    const int* __restrict__ eidx, const int* __restrict__ srcs,
    const int* __restrict__ dsts, float* __restrict__ lbuf4)
{
    __shared__ __align__(16) ushort As[EPB][264];    // e_enc, 16.9 KB
    __shared__ __align__(16) ushort XLR[64][264];    // 32 XL + 32 XR rows, 33.8 KB
    __shared__ float ea[EPB * 7];
    __shared__ int sArr[EPB], dArr[EPB];
    __shared__ float red[4][EPB];
    int j0 = blockIdx.x * EPB;
    int t = threadIdx.x, w = t >> 6, lane = t & 63;
    int l15 = lane & 15, l4 = lane >> 4;

    if (t < EPB * 7) {
        int e = eidx[j0 + t / 7];
        ea[t] = edge_attr[(size_t)e * 7 + t % 7];
    }
    if (t < EPB) {
        sArr[t] = srcs[j0 + t];
        dArr[t] = dsts[j0 + t];
    }
    __syncthreads();

    // ---- phase A: e_enc once ----
    {
        float w7[7];
#pragma unroll
        for (int k = 0; k < 7; k++) w7[k] = W_ee[k * HID + t];
        float bee = b_ee[t];
#pragma unroll 4
        for (int r = 0; r < EPB; r++) {
            float acc = bee;
#pragma unroll
            for (int k = 0; k < 7; k++) acc += w7[k] * ea[r * 7 + k];
            As[r][t] = f2bf(fmaxf(acc, 0.f));
        }
    }
    __syncthreads();

    int gr = t >> 2;            // staging row 0..63 (0-31 XL, 32-63 XR)
    int gc = (t & 3) * 64;      // col chunk: 64 ushorts = 128 B
    int eIdx = gr & 31;

    for (int h = 0; h < HEADS; h++) {
        // ---- MFMA for head h (reads As; gather staging overlaps) ----
        f32x4 acc[2][4] = {};
        for (int k0 = 0; k0 < 256; k0 += 32) {
            bf16x8 a[2], b[4];
#pragma unroll
            for (int rt = 0; rt < 2; rt++)
                a[rt] = *(const bf16x8*)&As[rt * 16 + l15][k0 + l4 * 8];
#pragma unroll
            for (int ct = 0; ct < 4; ct++) {
                int n = h * 256 + w * 64 + ct * 16 + l15;
                b[ct] = *(const bf16x8*)&WeT[(size_t)n * 256 + k0 + l4 * 8];
            }
#pragma unroll
            for (int rt = 0; rt < 2; rt++)
#pragma unroll
                for (int ct = 0; ct < 4; ct++)
                    acc[rt][ct] = __builtin_amdgcn_mfma_f32_16x16x32_bf16(
                        a[rt], b[ct], acc[rt][ct], 0, 0, 0);
        }

        // ---- stage all 64 gather rows for head h (8x16B per thread) ----
        {
            const ushort* src = (gr < 32)
                ? &xl[(size_t)sArr[eIdx] * 1024 + h * 256 + gc]
                : &xr[(size_t)dArr[eIdx] * 1024 + h * 256 + gc];
#pragma unroll
            for (int c = 0; c < 8; c++)
                *(bf16x8*)&XLR[gr][gc + c * 8] = *(const bf16x8*)&src[c * 8];
        }

        float bev[4], atv[4];
#pragma unroll
        for (int ct = 0; ct < 4; ct++) {
            int col = w * 64 + ct * 16 + l15;
            bev[ct] = b_e[h * 256 + col];
            atv[ct] = att[h * 256 + col];
        }
        __syncthreads();   // (1) staging done; prev head's red reads done

        // ---- logits for both 16-edge groups ----
        float lp[2][4];
#pragma unroll
        for (int rt = 0; rt < 2; rt++)
#pragma unroll
            for (int r = 0; r < 4; r++) {
                int li = rt * 16 + l4 * 4 + r;
                float p = 0.f;
#pragma unroll
                for (int ct = 0; ct < 4; ct++) {
                    int col = w * 64 + ct * 16 + l15;
                    float z = acc[rt][ct][r] + bev[ct] +
                              bf2f(XLR[li][col]) + bf2f(XLR[32 + li][col]);
                    z = (z > 0.f) ? z : 0.2f * z;
                    p += z * atv[ct];
                }
                lp[rt][r] = p;
            }
#pragma unroll
        for (int off = 1; off < 16; off <<= 1)
#pragma unroll
            for (int rt = 0; rt < 2; rt++)
#pragma unroll
                for (int r = 0; r < 4; r++)
                    lp[rt][r] += __shfl_xor(lp[rt][r], off);
        if (l15 == 0)
#pragma unroll
            for (int rt = 0; rt < 2; rt++)
#pragma unroll
                for (int r = 0; r < 4; r++)
                    red[w][rt * 16 + l4 * 4 + r] = lp[rt][r];
        __syncthreads();   // (2) red complete; XLR reads complete

        if (t < EPB) {
            float v = red[0][t] + red[1][t] + red[2][t] + red[3][t];
            lbuf4[(size_t)(j0 + t) * 4 + h] = v;
        }
        // next head's red write is after its sync(1); XLR rewrite safe after (2)
    }
}

// ---------------------------------------------------------------------------
// Fused segment softmax + aggregation, ALL HEADS: block = node, wave = head.
__global__ __launch_bounds__(256) void softmax_agg_kernel(
    const float* __restrict__ lbuf4, const int* __restrict__ rowptr,
    const int* __restrict__ srcs, const ushort* __restrict__ xl,
    ushort* __restrict__ agg)
{
    int n = blockIdx.x;
    int h = threadIdx.x >> 6, lane = threadIdx.x & 63;
    int r0 = rowptr[n], r1 = rowptr[n + 1];
    float m = -3.4e38f;
    for (int j = r0; j < r1; j++)
        m = fmaxf(m, lbuf4[(size_t)j * 4 + h]);
    float denom = 0.f;
    for (int j = r0; j < r1; j++)
        denom += __expf(lbuf4[(size_t)j * 4 + h] - m);
    float rd = (denom > 0.f) ? 1.f / denom : 0.f;
    float a0 = 0.f, a1 = 0.f, a2 = 0.f, a3 = 0.f;
    for (int j = r0; j < r1; j++) {
        int s = srcs[j];
        float alpha = __expf(lbuf4[(size_t)j * 4 + h] - m) * rd;
        ushort4 xv = *(const ushort4*)&xl[(size_t)s * 1024 + h * 256 + lane * 4];
        a0 += alpha * bf2f(xv.x); a1 += alpha * bf2f(xv.y);
        a2 += alpha * bf2f(xv.z); a3 += alpha * bf2f(xv.w);
    }
    ushort4 o;
    o.x = f2bf(a0); o.y = f2bf(a1); o.z = f2bf(a2); o.w = f2bf(a3);
    *(ushort4*)&agg[(size_t)n * 1024 + h * 256 + lane * 4] = o;
}

// ---------------------------------------------------------------------------
// out = sigmoid(hid_bf @ W_d2 + b_d2)   hid:[N,256] bf16, W:[256,6]
__global__ __launch_bounds__(256) void final_kernel(
    const ushort* __restrict__ hid, const float* __restrict__ W_d2,
    const float* __restrict__ b_d2, float* __restrict__ out)
{
    int g = blockIdx.x * blockDim.x + threadIdx.x;
    if (g >= NN * 6) return;
    int n = g / 6, j = g % 6;
    float acc = b_d2[j];
    const bf16x8* hp = reinterpret_cast<const bf16x8*>(&hid[(size_t)n * HID]);
#pragma unroll 4
    for (int k8 = 0; k8 < HID / 8; k8++) {
        bf16x8 hv = hp[k8];
#pragma unroll
        for (int i = 0; i < 8; i++)
            acc += bf2f((ushort)hv[i]) * W_d2[(k8 * 8 + i) * 6 + j];
    }
    out[g] = 1.f / (1.f + __expf(-acc));
}

// ---------------------------------------------------------------------------
extern "C" void kernel_launch(void* const* d_in, const int* in_sizes, int n_in,
                              void* d_out, int out_size, void* d_ws, size_t ws_size,
                              hipStream_t stream)
{
    const float* x         = (const float*)d_in[0];
    const float* edge_attr = (const float*)d_in[1];
    const float* W_ne = (const float*)d_in[2];  const float* b_ne = (const float*)d_in[3];
    const float* W_ee = (const float*)d_in[4];  const float* b_ee = (const float*)d_in[5];
    const float* W_l  = (const float*)d_in[6];  const float* b_l  = (const float*)d_in[7];
    const float* W_r  = (const float*)d_in[8];  const float* b_r  = (const float*)d_in[9];
    const float* W_e  = (const float*)d_in[10]; const float* b_e  = (const float*)d_in[11];
    const float* att  = (const float*)d_in[12];
    const float* conv_bias = (const float*)d_in[13];
    const float* W_d1 = (const float*)d_in[14]; const float* b_d1 = (const float*)d_in[15];
    const float* W_d2 = (const float*)d_in[16]; const float* b_d2 = (const float*)d_in[17];
    const int*   ei   = (const int*)d_in[18];
    float* out = (float*)d_out;

    const size_t NODE256  = (size_t)NN * HID;   // 5.12M
    const size_t NODE1024 = (size_t)NN * HO;    // 20.48M
    char* p = (char*)d_ws;
    ushort* h_bf   = (ushort*)p;  p += NODE256 * 2;    // 10.24 MB; reused as hid
    ushort* xl_bf  = (ushort*)p;  p += NODE1024 * 2;   // 40.96 MB
    ushort* xr_bf  = (ushort*)p;  p += NODE1024 * 2;   // 40.96 MB; reused as agg
    float*  lbuf4  = (float*)p;   p += (size_t)NE * HEADS * 4;
    int*    deg    = (int*)p;     p += (size_t)NN * 4;
    int*    rowptr = (int*)p;     p += (size_t)(NN + 1) * 4;
    int*    cursor = (int*)p;     p += (size_t)NN * 4;
    int*    eidx   = (int*)p;     p += (size_t)NE * 4;
    int*    srcs   = (int*)p;     p += (size_t)NE * 4;
    int*    dsts   = (int*)p;     p += (size_t)NE * 4;
    float*  biasH  = (float*)p;   p += HID * 4;
    ushort* WlT    = (ushort*)p;  p += (size_t)HO * HID * 2;   // [1024][256]
    ushort* WrT    = (ushort*)p;  p += (size_t)HO * HID * 2;
    ushort* WeT    = (ushort*)p;  p += (size_t)HO * HID * 2;
    ushort* Wd1T   = (ushort*)p;  p += (size_t)HID * HO * 2;   // [256][1024]
    if ((size_t)(p - (char*)d_ws) > ws_size) return;  // clean fail, no OOB

    ushort* agg_bf = xr_bf;   // xr dead after edge kernel
    ushort* hid_bf = h_bf;    // h dead after xl/xr GEMMs

    hipMemsetAsync(deg, 0, (size_t)NN * 4, stream);

    node_enc_kernel<<<NN, 256, 0, stream>>>(x, W_ne, b_ne, h_bf);
    biasH_kernel<<<1, 256, 0, stream>>>(conv_bias, W_d1, b_d1, biasH);

    transpose_bf16_kernel<<<dim3(HID, HO / 256), 256, 0, stream>>>(W_l,  WlT,  HID, HO);
    transpose_bf16_kernel<<<dim3(HID, HO / 256), 256, 0, stream>>>(W_r,  WrT,  HID, HO);
    transpose_bf16_kernel<<<dim3(HID, HO / 256), 256, 0, stream>>>(W_e,  WeT,  HID, HO);
    transpose_bf16_kernel<<<dim3(HO, HID / 256), 256, 0, stream>>>(W_d1, Wd1T, HO,  HID);

    hist_kernel<<<(NE + 255) / 256, 256, 0, stream>>>(ei, deg);
    scan_kernel<<<1, 1024, 0, stream>>>(deg, rowptr, cursor);
    scatter_kernel<<<(NE + 255) / 256, 256, 0, stream>>>(ei, cursor, eidx, srcs, dsts);

    const int gemmGrid = (NN + 63) / 64;     // 313

    // xl, xr: all heads in one dispatch each
    qkv_gemm_kernel<<<dim3(gemmGrid, 4), 256, 0, stream>>>(h_bf, WlT, b_l, xl_bf, NN);
    qkv_gemm_kernel<<<dim3(gemmGrid, 4), 256, 0, stream>>>(h_bf, WrT, b_r, xr_bf, NN);

    // edge logits, all heads
    edge_mfma_logits_kernel<<<NE / EPB, 256, 0, stream>>>(
        edge_attr, W_ee, b_ee, WeT, b_e, att, xl_bf, xr_bf,
        eidx, srcs, dsts, lbuf4);

    // segment softmax + aggregation, all heads (writes agg into xr buffer)
    softmax_agg_kernel<<<NN, 256, 0, stream>>>(lbuf4, rowptr, srcs, xl_bf, agg_bf);

    // decoder layer 1: K=1024, fused bias+relu, bf16 out (into h buffer)
    dec_gemm_kernel<<<gemmGrid, 256, 0, stream>>>(agg_bf, Wd1T, biasH, hid_bf, NN);

    // decoder layer 2 + sigmoid
    final_kernel<<<(NN * 6 + 255) / 256, 256, 0, stream>>>(hid_bf, W_d2, b_d2, out);
}